// Round 5
// baseline (57.232 us; speedup 1.0000x reference)
//
#include <hip/hip_runtime.h>
#include <hip/hip_bf16.h>
#include <math.h>

typedef __attribute__((ext_vector_type(8))) short short8;
typedef __attribute__((ext_vector_type(4))) float f32x4;

static __device__ __forceinline__ unsigned short f2bf(float f) {
    __hip_bfloat16 h = __float2bfloat16(f);
    return *reinterpret_cast<unsigned short*>(&h);
}

// Prep: W1f in per-lane MFMA fragment layout [h][s][nt][lane] (short8 each):
// entry value j = bf16( W1[h*128 + (s*4 + lane>>4)*8 + j][nt*16 + (lane&15)] ).
// ep_gemm's B-fragment load is then ONE coalesced global b128 per (s,nt):
// 64 lanes x 16 B = 1 KiB contiguous, L2-hot (64 KiB table).
__global__ __launch_bounds__(256) void ep_prepw(
    const float* __restrict__ W1, unsigned short* __restrict__ W1f)
{
    const int gid  = blockIdx.x * 256 + threadIdx.x;  // 4096 = 2*4*8*64
    const int lane = gid & 63;
    const int nt   = (gid >> 6) & 7;
    const int s    = (gid >> 9) & 3;
    const int h    = gid >> 11;
    const int kk   = s * 4 + (lane >> 4);
    const int col  = nt * 16 + (lane & 15);
    short8 v;
    #pragma unroll
    for (int j = 0; j < 8; ++j)
        v[j] = (short)f2bf(W1[(size_t)(h * 128 + kk * 8 + j) * 128 + col]);
    reinterpret_cast<short8*>(W1f)[gid] = v;
}

// Phase 1: A = x@W1top (+b1 folded), B = x@W1bot, int8 per-row-scale quant.
// Block = 128 nodes x all 128 cols, h = gi&1 selects the W1 half.
// Hidden-unit PERMUTATION sigma(p) = (p&7)*16 + (p>>3): stored byte p of a row
// holds quantized unit sigma(p), making each lane's 8 quant values contiguous
// -> one uint2 store per (mt,r2); a 16-lane group writes one 128 B line.
// (The final dot over hidden units is permutation-invariant; ep_edges indexes
// W2 with sigma. b1 is folded BEFORE permutation so no change there.)
#define BM 128

__global__ __launch_bounds__(256) void ep_gemm(
    const float* __restrict__ x, const unsigned short* __restrict__ W1f,
    const float* __restrict__ b1,
    signed char* __restrict__ Aq, signed char* __restrict__ Bq,
    float* __restrict__ Ascale, float* __restrict__ Bscale,
    int nNodes, int nwg)
{
    __shared__ short8 xs[16 * BM];   // 32 KiB only -> 4 blocks/CU

    const int tid = threadIdx.x;

    // bijective XCD grouping: the two h-siblings of an Mblk share an XCD
    const int orig = blockIdx.x;
    const int q = nwg >> 3, r = nwg & 7;
    const int xcd = orig & 7, within = orig >> 3;
    const int base = (xcd < r) ? xcd * (q + 1) : r * (q + 1) + (xcd - r) * q;
    const int gi = base + within;

    const int Mblk  = gi >> 1;
    const int h     = gi & 1;
    const int node0 = Mblk * BM;
    signed char* __restrict__ outq = h ? Bq : Aq;
    float* __restrict__ outs = h ? Bscale : Ascale;

    // stage x tile (swizzled slot kb*128 + (row^kb): conflict-free)
    #pragma unroll
    for (int i = 0; i < 8; ++i) {
        const int c = tid + i * 256;
        const int row = c >> 4, kb = c & 15;
        const int node = node0 + row;
        short8 v;
        if (node < nNodes) {
            const float4* src = reinterpret_cast<const float4*>(x + (size_t)node * 128 + kb * 8);
            const float4 p0 = src[0], p1 = src[1];
            v[0] = (short)f2bf(p0.x); v[1] = (short)f2bf(p0.y);
            v[2] = (short)f2bf(p0.z); v[3] = (short)f2bf(p0.w);
            v[4] = (short)f2bf(p1.x); v[5] = (short)f2bf(p1.y);
            v[6] = (short)f2bf(p1.z); v[7] = (short)f2bf(p1.w);
        } else {
            v = short8{0, 0, 0, 0, 0, 0, 0, 0};
        }
        xs[kb * BM + (row ^ kb)] = v;
    }
    __syncthreads();

    const int w = tid >> 6, lane = tid & 63;
    const int wm = w * 32;
    const int lrow = lane & 15, lkb = lane >> 4;
    const short8* __restrict__ Wf = reinterpret_cast<const short8*>(W1f) + (size_t)h * 2048;

    f32x4 acc[2][8];
    #pragma unroll
    for (int mt = 0; mt < 2; ++mt)
        #pragma unroll
        for (int nt = 0; nt < 8; ++nt)
            acc[mt][nt] = f32x4{0.f, 0.f, 0.f, 0.f};

    #pragma unroll
    for (int s = 0; s < 4; ++s) {
        const int kk = s * 4 + lkb;
        short8 af[2], bfr[8];
        #pragma unroll
        for (int mt = 0; mt < 2; ++mt)
            af[mt] = xs[kk * BM + ((wm + mt * 16 + lrow) ^ kk)];
        #pragma unroll
        for (int nt = 0; nt < 8; ++nt)
            bfr[nt] = Wf[(s * 8 + nt) * 64 + lane];   // coalesced, L2-hot
        #pragma unroll
        for (int mt = 0; mt < 2; ++mt)
            #pragma unroll
            for (int nt = 0; nt < 8; ++nt)
                acc[mt][nt] = __builtin_amdgcn_mfma_f32_16x16x32_bf16(
                    af[mt], bfr[nt], acc[mt][nt], 0, 0, 0);
    }

    // fold b1 into A (pre-permutation): lane's col for nt is nt*16+lrow
    float b1v[8];
    #pragma unroll
    for (int nt = 0; nt < 8; ++nt)
        b1v[nt] = (h == 0) ? b1[nt * 16 + lrow] : 0.f;

    // C/D: col = lane&15, row = (lane>>4)*4 + reg. Row-max via shfl over the
    // 16 lanes sharing lane>>4; lanes of a group hold the SAME row -> the
    // uint2 stores of a group cover one contiguous 128 B line.
    const int crow0 = (lane >> 4) * 4;
    #pragma unroll
    for (int mt = 0; mt < 2; ++mt) {
        #pragma unroll
        for (int r2 = 0; r2 < 4; ++r2) {
            float v[8];
            float m = 0.f;
            #pragma unroll
            for (int nt = 0; nt < 8; ++nt) {
                v[nt] = acc[mt][nt][r2] + b1v[nt];
                m = fmaxf(m, fabsf(v[nt]));
            }
            m = fmaxf(m, __shfl_xor(m, 1));
            m = fmaxf(m, __shfl_xor(m, 2));
            m = fmaxf(m, __shfl_xor(m, 4));
            m = fmaxf(m, __shfl_xor(m, 8));
            const float inv = 127.0f / fmaxf(m, 1e-30f);
            const int row = node0 + wm + mt * 16 + crow0 + r2;
            if (row < nNodes) {
                unsigned lo = 0, hi = 0;
                #pragma unroll
                for (int nt = 0; nt < 4; ++nt)
                    lo |= ((unsigned)(unsigned char)(signed char)(int)rintf(v[nt] * inv)) << (8 * nt);
                #pragma unroll
                for (int nt = 4; nt < 8; ++nt)
                    hi |= ((unsigned)(unsigned char)(signed char)(int)rintf(v[nt] * inv)) << (8 * (nt - 4));
                *reinterpret_cast<uint2*>(outq + (size_t)row * 128 + lrow * 8) =
                    make_uint2(lo, hi);
                if (lrow == 0) outs[row] = m * (1.0f / 127.0f);
            }
        }
    }
}

// Phase 2: out[e] = sigmoid( sum_p relu(Aq[r][p]*sa + Bq[c][p]*sb) * W2[sigma(p)] + b2 )
// 16 lanes/edge, lane sub owns bytes [sub*8, sub*8+8) = units sigma(sub*8+j) = j*16+sub.
// Unrolled 2 edges/iter so 4 row-gathers are in flight per compute step.
__global__ __launch_bounds__(256) void ep_edges(
    const int* __restrict__ ei,
    const signed char* __restrict__ Aq, const signed char* __restrict__ Bq,
    const float* __restrict__ Ascale, const float* __restrict__ Bscale,
    const float* __restrict__ W2, const float* __restrict__ b2,
    float* __restrict__ out, int E)
{
    const int sub = threadIdx.x & 15;
    float w2f[8];
    #pragma unroll
    for (int j = 0; j < 8; ++j) w2f[j] = W2[j * 16 + sub];   // sigma(sub*8+j)
    const float b2v = b2[0];

    const size_t gsz = ((size_t)gridDim.x * blockDim.x) >> 4;
    const size_t g0 = ((size_t)blockIdx.x * blockDim.x + threadIdx.x) >> 4;

    for (size_t e = g0; e < (size_t)E; e += 2 * gsz) {
        const size_t e2 = e + gsz;
        const bool has2 = e2 < (size_t)E;

        const size_t r1 = (size_t)(unsigned)ei[e];
        const size_t c1 = (size_t)(unsigned)ei[E + e];
        const uint2 qa1 = *reinterpret_cast<const uint2*>(Aq + r1 * 128 + sub * 8);
        const uint2 qb1 = *reinterpret_cast<const uint2*>(Bq + c1 * 128 + sub * 8);
        const float sa1 = Ascale[r1];
        const float sb1 = Bscale[c1];

        uint2 qa2 = make_uint2(0, 0), qb2 = make_uint2(0, 0);
        float sa2 = 0.f, sb2 = 0.f;
        if (has2) {
            const size_t r2 = (size_t)(unsigned)ei[e2];
            const size_t c2 = (size_t)(unsigned)ei[E + e2];
            qa2 = *reinterpret_cast<const uint2*>(Aq + r2 * 128 + sub * 8);
            qb2 = *reinterpret_cast<const uint2*>(Bq + c2 * 128 + sub * 8);
            sa2 = Ascale[r2];
            sb2 = Bscale[c2];
        }

        float p1 = 0.f, p2 = 0.f;
        #pragma unroll
        for (int j = 0; j < 8; ++j) {
            const int sh = 8 * (j & 3);
            const int ia1 = (int)(signed char)(((j < 4) ? qa1.x : qa1.y) >> sh);
            const int ib1 = (int)(signed char)(((j < 4) ? qb1.x : qb1.y) >> sh);
            const float h1 = fmaxf(fmaf((float)ia1, sa1, (float)ib1 * sb1), 0.f);
            p1 = fmaf(h1, w2f[j], p1);
            const int ia2 = (int)(signed char)(((j < 4) ? qa2.x : qa2.y) >> sh);
            const int ib2 = (int)(signed char)(((j < 4) ? qb2.x : qb2.y) >> sh);
            const float h2 = fmaxf(fmaf((float)ia2, sa2, (float)ib2 * sb2), 0.f);
            p2 = fmaf(h2, w2f[j], p2);
        }

        p1 += __shfl_xor(p1, 1); p2 += __shfl_xor(p2, 1);
        p1 += __shfl_xor(p1, 2); p2 += __shfl_xor(p2, 2);
        p1 += __shfl_xor(p1, 4); p2 += __shfl_xor(p2, 4);
        p1 += __shfl_xor(p1, 8); p2 += __shfl_xor(p2, 8);

        if (sub == 0) {
            out[e] = 1.f / (1.f + expf(-(p1 + b2v)));
            if (has2) out[e2] = 1.f / (1.f + expf(-(p2 + b2v)));
        }
    }
}

extern "C" void kernel_launch(void* const* d_in, const int* in_sizes, int n_in,
                              void* d_out, int out_size, void* d_ws, size_t ws_size,
                              hipStream_t stream) {
    const float* x  = (const float*)d_in[0];
    const int*   ei = (const int*)  d_in[1];
    const float* W1 = (const float*)d_in[2];
    const float* b1 = (const float*)d_in[3];
    const float* W2 = (const float*)d_in[4];
    const float* b2 = (const float*)d_in[5];
    float* out = (float*)d_out;

    const int nNodes = in_sizes[0] / 128;     // 50000
    const int E      = in_sizes[1] / 2;       // 600000

    unsigned short* W1f = (unsigned short*)d_ws;                 // 64 KiB
    signed char* Aq     = (signed char*)(W1f + 4096 * 8);        // nNodes*128
    signed char* Bq     = Aq + (size_t)nNodes * 128;             // nNodes*128
    float* Ascale       = (float*)(Bq + (size_t)nNodes * 128);   // nNodes f32
    float* Bscale       = Ascale + nNodes;                       // nNodes f32

    ep_prepw<<<16, 256, 0, stream>>>(W1, W1f);

    const int mblocks = (nNodes + BM - 1) / BM;
    const int nwg = mblocks * 2;
    ep_gemm<<<nwg, 256, 0, stream>>>(x, W1f, b1, Aq, Bq, Ascale, Bscale, nNodes, nwg);

    const int needed = (int)(((size_t)E * 16 + 255) / 256);
    const int edge_blocks = needed < 4096 ? needed : 4096;
    ep_edges<<<edge_blocks, 256, 0, stream>>>(ei, Aq, Bq, Ascale, Bscale, W2, b2, out, E);
}

// Round 6
// 47.539 us; speedup vs baseline: 1.2039x; 1.2039x over previous
//
#include <hip/hip_runtime.h>
#include <hip/hip_bf16.h>
#include <math.h>

typedef __attribute__((ext_vector_type(8))) short short8;
typedef __attribute__((ext_vector_type(4))) float f32x4;

static __device__ __forceinline__ unsigned short f2bf(float f) {
    __hip_bfloat16 h = __float2bfloat16(f);
    return *reinterpret_cast<unsigned short*>(&h);
}

// byte b of word u -> float (v_cvt_f32_ubyteN — LLVM pattern-matches this)
static __device__ __forceinline__ float ub2f(unsigned u, int b) {
    return (float)((u >> (8 * b)) & 0xffu);
}

// Prep: W1s[h][kb][col] (short8): j-th value = bf16(W1[h*128+kb*8+j][col]).
// Exactly the ws LDS layout ep_gemm stages -> gemm W staging is a linear copy.
__global__ __launch_bounds__(256) void ep_prepw(
    const float* __restrict__ W1, unsigned short* __restrict__ W1s)
{
    const int gid = blockIdx.x * 256 + threadIdx.x;   // 4096 = 2*16*128
    const int h   = gid >> 11;
    const int kb  = (gid >> 7) & 15;
    const int col = gid & 127;
    short8 v;
    #pragma unroll
    for (int j = 0; j < 8; ++j)
        v[j] = (short)f2bf(W1[(size_t)(h * 128 + kb * 8 + j) * 128 + col]);
    reinterpret_cast<short8*>(W1s)[gid] = v;
}

// Phase 1: A = x@W1top (+b1), B = x@W1bot, quantized to (int8+128) stored as
// uchar, per-row scale = rowmax/127. BM=64 rows x 128 cols per block (48 KiB
// LDS -> 3 blocks/CU). 4 waves, wave = 16 rows x 128 cols (acc[8] f32x4 = 32 VGPR).
// Permutation: stored byte p of a row holds unit sigma(p) = (p&7)*16 + (p>>3),
// so each lane's 8 quant values are contiguous -> one uint2 store per r2,
// a 16-lane group covers one 128 B line. ep_edges indexes W2 by sigma.
#define BM 64

__global__ __launch_bounds__(256) void ep_gemm(
    const float* __restrict__ x, const unsigned short* __restrict__ W1s,
    const float* __restrict__ b1,
    unsigned char* __restrict__ Aq, unsigned char* __restrict__ Bq,
    float* __restrict__ Ascale, float* __restrict__ Bscale,
    int nNodes, int nwg)
{
    __shared__ short8 xs[16 * BM];   // 16 KiB: [kb][row^kb]
    __shared__ short8 ws[16 * 128];  // 32 KiB: [kb][col]

    const int tid = threadIdx.x;

    // bijective XCD grouping: the two h-siblings of an Mblk land on one XCD
    const int orig = blockIdx.x;
    const int q = nwg >> 3, r = nwg & 7;
    const int xcd = orig & 7, within = orig >> 3;
    const int base = (xcd < r) ? xcd * (q + 1) : r * (q + 1) + (xcd - r) * q;
    const int gi = base + within;

    const int Mblk  = gi >> 1;
    const int h     = gi & 1;
    const int node0 = Mblk * BM;
    unsigned char* __restrict__ outq = h ? Bq : Aq;
    float* __restrict__ outs = h ? Bscale : Ascale;

    // stage x tile: 1024 chunks (row,kb); swizzled slot kb*64+(row^kb) is
    // conflict-free for both the write and the fragment read (row^kb < 64)
    #pragma unroll
    for (int i = 0; i < 4; ++i) {
        const int c = tid + i * 256;
        const int row = c >> 4, kb = c & 15;
        const int node = node0 + row;
        short8 v;
        if (node < nNodes) {
            const float4* src = reinterpret_cast<const float4*>(x + (size_t)node * 128 + kb * 8);
            const float4 p0 = src[0], p1 = src[1];
            v[0] = (short)f2bf(p0.x); v[1] = (short)f2bf(p0.y);
            v[2] = (short)f2bf(p0.z); v[3] = (short)f2bf(p0.w);
            v[4] = (short)f2bf(p1.x); v[5] = (short)f2bf(p1.y);
            v[6] = (short)f2bf(p1.z); v[7] = (short)f2bf(p1.w);
        } else {
            v = short8{0, 0, 0, 0, 0, 0, 0, 0};
        }
        xs[kb * BM + (row ^ kb)] = v;
    }
    // stage W half: linear 32 KiB b128 copy from W1s (L2-hot)
    #pragma unroll
    for (int i = 0; i < 8; ++i) {
        const int c = tid + i * 256;
        ws[c] = reinterpret_cast<const short8*>(W1s)[h * 2048 + c];
    }
    __syncthreads();

    const int w = tid >> 6, lane = tid & 63;
    const int wm = w * 16;
    const int lrow = lane & 15, lkb = lane >> 4;

    f32x4 acc[8];
    #pragma unroll
    for (int nt = 0; nt < 8; ++nt) acc[nt] = f32x4{0.f, 0.f, 0.f, 0.f};

    #pragma unroll
    for (int s = 0; s < 4; ++s) {
        const int kk = s * 4 + lkb;
        const short8 af = xs[kk * BM + ((wm + lrow) ^ kk)];
        short8 bfr[8];
        #pragma unroll
        for (int nt = 0; nt < 8; ++nt)
            bfr[nt] = ws[kk * 128 + nt * 16 + lrow];
        #pragma unroll
        for (int nt = 0; nt < 8; ++nt)
            acc[nt] = __builtin_amdgcn_mfma_f32_16x16x32_bf16(af, bfr[nt], acc[nt], 0, 0, 0);
    }

    // fold b1 into A (pre-permutation): lane's col for nt is nt*16+lrow
    float b1v[8];
    #pragma unroll
    for (int nt = 0; nt < 8; ++nt)
        b1v[nt] = (h == 0) ? b1[nt * 16 + lrow] : 0.f;

    // C/D: col = lane&15, row = (lane>>4)*4 + reg. Row-max via shfl over the
    // 16 lanes sharing lane>>4 (same row). Store q+128 as uchar, uint2/lane.
    const int crow0 = (lane >> 4) * 4;
    #pragma unroll
    for (int r2 = 0; r2 < 4; ++r2) {
        float v[8];
        float m = 0.f;
        #pragma unroll
        for (int nt = 0; nt < 8; ++nt) {
            v[nt] = acc[nt][r2] + b1v[nt];
            m = fmaxf(m, fabsf(v[nt]));
        }
        m = fmaxf(m, __shfl_xor(m, 1));
        m = fmaxf(m, __shfl_xor(m, 2));
        m = fmaxf(m, __shfl_xor(m, 4));
        m = fmaxf(m, __shfl_xor(m, 8));
        const float inv = 127.0f / fmaxf(m, 1e-30f);
        const int row = node0 + wm + crow0 + r2;
        if (row < nNodes) {
            unsigned lo = 0, hi = 0;
            #pragma unroll
            for (int nt = 0; nt < 4; ++nt)
                lo |= ((unsigned)(int)rintf(fmaf(v[nt], inv, 128.0f))) << (8 * nt);
            #pragma unroll
            for (int nt = 4; nt < 8; ++nt)
                hi |= ((unsigned)(int)rintf(fmaf(v[nt], inv, 128.0f))) << (8 * (nt - 4));
            *reinterpret_cast<uint2*>(outq + (size_t)row * 128 + lrow * 8) =
                make_uint2(lo, hi);
            if (lrow == 0) outs[row] = m * (1.0f / 127.0f);
        }
    }
}

// Phase 2: out[e] = sigmoid( sum_p relu((Aq-128)*sa + (Bq-128)*sb) * W2[sigma] + b2 )
// 8 lanes/edge; lane sub owns bytes [sub*16, sub*16+16) = one uint4 per side
// (row = 128 B = 8 lanes x 16 B, perfectly coalesced). Dequant via ubyte->f32
// cvt with the -128 folded into off = -128*(sa+sb): 6 VALU per element.
__global__ __launch_bounds__(256) void ep_edges(
    const int* __restrict__ ei,
    const unsigned char* __restrict__ Aq, const unsigned char* __restrict__ Bq,
    const float* __restrict__ Ascale, const float* __restrict__ Bscale,
    const float* __restrict__ W2, const float* __restrict__ b2,
    float* __restrict__ out, int E)
{
    const int sub = threadIdx.x & 7;
    // byte p = sub*16+j  ->  unit sigma(p) = (j&7)*16 + sub*2 + (j>>3)
    float w2f[16];
    #pragma unroll
    for (int j = 0; j < 16; ++j)
        w2f[j] = W2[(j & 7) * 16 + sub * 2 + (j >> 3)];
    const float b2v = b2[0];

    const size_t stride = ((size_t)gridDim.x * blockDim.x) >> 3;
    for (size_t e = ((size_t)blockIdx.x * blockDim.x + threadIdx.x) >> 3;
         e < (size_t)E; e += stride) {
        const size_t r = (size_t)(unsigned)ei[e];
        const size_t c = (size_t)(unsigned)ei[E + e];

        const uint4 qa = *reinterpret_cast<const uint4*>(Aq + r * 128 + sub * 16);
        const uint4 qb = *reinterpret_cast<const uint4*>(Bq + c * 128 + sub * 16);
        const float sa = Ascale[r];
        const float sb = Bscale[c];
        const float off = -128.0f * (sa + sb);

        float p = 0.f;
        const unsigned wa[4] = {qa.x, qa.y, qa.z, qa.w};
        const unsigned wb[4] = {qb.x, qb.y, qb.z, qb.w};
        #pragma unroll
        for (int wd = 0; wd < 4; ++wd) {
            #pragma unroll
            for (int b = 0; b < 4; ++b) {
                float t = fmaf(ub2f(wa[wd], b), sa, off);
                t = fmaf(ub2f(wb[wd], b), sb, t);
                p = fmaf(fmaxf(t, 0.f), w2f[wd * 4 + b], p);
            }
        }

        p += __shfl_xor(p, 1);
        p += __shfl_xor(p, 2);
        p += __shfl_xor(p, 4);

        if (sub == 0) out[e] = 1.f / (1.f + expf(-(p + b2v)));
    }
}

extern "C" void kernel_launch(void* const* d_in, const int* in_sizes, int n_in,
                              void* d_out, int out_size, void* d_ws, size_t ws_size,
                              hipStream_t stream) {
    const float* x  = (const float*)d_in[0];
    const int*   ei = (const int*)  d_in[1];
    const float* W1 = (const float*)d_in[2];
    const float* b1 = (const float*)d_in[3];
    const float* W2 = (const float*)d_in[4];
    const float* b2 = (const float*)d_in[5];
    float* out = (float*)d_out;

    const int nNodes = in_sizes[0] / 128;     // 50000
    const int E      = in_sizes[1] / 2;       // 600000

    unsigned short* W1s = (unsigned short*)d_ws;                 // 64 KiB
    unsigned char* Aq   = (unsigned char*)(W1s + 4096 * 8);      // nNodes*128
    unsigned char* Bq   = Aq + (size_t)nNodes * 128;             // nNodes*128
    float* Ascale       = (float*)(Bq + (size_t)nNodes * 128);   // nNodes f32
    float* Bscale       = Ascale + nNodes;                       // nNodes f32

    ep_prepw<<<16, 256, 0, stream>>>(W1, W1s);

    const int mblocks = (nNodes + BM - 1) / BM;
    const int nwg = mblocks * 2;
    ep_gemm<<<nwg, 256, 0, stream>>>(x, W1s, b1, Aq, Bq, Ascale, Bscale, nNodes, nwg);

    const int edge_blocks = 2048;   // grid-stride; 8 lanes/edge
    ep_edges<<<edge_blocks, 256, 0, stream>>>(ei, Aq, Bq, Ascale, Bscale, W2, b2, out, E);
}